// Round 9
// baseline (8336.360 us; speedup 1.0000x reference)
//
#include <hip/hip_runtime.h>
#include <hip/hip_bf16.h>
#include <math.h>
#include <stdint.h>

// SimpleSSMLayer on gfx950 — Round 9: OUTPUT IS FP32.
// Resolution of the 0.709 saga: inputs fp32 (proven on-device R5/R6), output
// fp32 per the harness contract ("else float*") — the test label's "bf16" is
// a hardcoded template string. My bf16 writes half-filled the fp32 buffer;
// fp32-decode of bf16 pairs == the observed bit-identical 0.709 signature.
// This round = R8's exact pipeline with fp32 output writes (kpre/k2 only).
// ws layout (bytes):
//   [0)        meanDv (float)                     pad to 256
//   [256)      h state: DI*DS fp32      = 131072
//   [131328)   XINc: (Tc+3)*DI bf16     = 1060864   rows 0..2 = conv tail
//   [1192192)  ZSc:  Tc*DI bf16         = 1048576
//   [2240768)  Gc:   Tc*DI bf16         = 1048576   total 3,289,344 B

using bf16 = __hip_bfloat16;

static constexpr int Bdim = 4;
static constexpr int Tdim = 2048;
static constexpr int DM   = 1024;
static constexpr int DI   = 2048;
static constexpr int DS   = 16;
static constexpr int DC   = 4;
static constexpr int DTR  = 32;
static constexpr int Tc   = 256;            // chunk rows
static constexpr int Mrows = Bdim * Tdim;   // 8192

__device__ __forceinline__ float b2f(bf16 v) { return __bfloat162float(v); }
__device__ __forceinline__ bf16  f2b(float v) { return __float2bfloat16(v); }
__device__ __forceinline__ float silu_f(float v) { return v / (1.0f + __expf(-v)); }
__device__ __forceinline__ float softplus_f(float v) {
  return (v > 15.0f) ? v : log1pf(__expf(v));
}

// --------------------------------------------------------------------------
__global__ __launch_bounds__(256)
void kmean(const float* __restrict__ Dv, float* __restrict__ meanp) {
  __shared__ float red[256];
  float s = 0.0f;
  for (int i = threadIdx.x; i < DI; i += 256) s += Dv[i];
  red[threadIdx.x] = s;
  __syncthreads();
  for (int o = 128; o > 0; o >>= 1) {
    if (threadIdx.x < o) red[threadIdx.x] += red[threadIdx.x + o];
    __syncthreads();
  }
  if (threadIdx.x == 0) *meanp = red[0] / (float)DI;
}

// out = meanDv * x + bo  (fp32) — the dominant term, in isolation.
__global__ __launch_bounds__(256)
void kpre(const float* __restrict__ x, const float* __restrict__ bo,
          const float* __restrict__ meanp, float* __restrict__ out) {
  const int col = blockIdx.x * 256 + threadIdx.x;      // 0..DM-1
  const size_t i = (size_t)blockIdx.y * DM + col;
  out[i] = (*meanp) * x[i] + bo[col];
}

// zero conv-tail rows 0..2 of XINc (batch start)
__global__ __launch_bounds__(256)
void kzero(bf16* __restrict__ XIN) {
  const int i = blockIdx.x * 256 + threadIdx.x;
  if (i < 3 * DI) XIN[i] = f2b(0.0f);
}

// copy prev chunk's last 3 x_in rows (storage rows Tc..Tc+2) -> rows 0..2
__global__ __launch_bounds__(256)
void ktail(bf16* __restrict__ XIN) {
  const int i = blockIdx.x * 256 + threadIdx.x;
  if (i < 3 * DI) XIN[i] = XIN[(size_t)Tc * DI + i];
}

// --------------------------------------------------------------------------
// k1: chunk GEMM  xz = xchunk @ Wi^T + bi ; x_in -> XIN rows 3..Tc+2,
// silu(z) -> ZS rows 0..Tc-1.  xchunk: (Tc x DM) fp32. Grid (2*DI/64, Tc/64).
// --------------------------------------------------------------------------
__global__ __launch_bounds__(256)
void k1(const float* __restrict__ A, const float* __restrict__ W,
        const float* __restrict__ bi,
        bf16* __restrict__ XIN, bf16* __restrict__ ZS)
{
  __shared__ float As[64][36];
  __shared__ float Bs[64][36];
  const int tid = threadIdx.x;
  const int bm = blockIdx.y * 64;
  const int bn = blockIdx.x * 64;
  const int tr = tid >> 4, tc = tid & 15;
  const int lr = tid >> 2, lc = (tid & 3) * 8;
  const int K = DM;

  float acc[4][4] = {};
  for (int k0 = 0; k0 < K; k0 += 32) {
    __syncthreads();
    {
      const float* ga = A + (size_t)(bm + lr) * K + k0 + lc;
      const float* gb = W + (size_t)(bn + lr) * K + k0 + lc;
#pragma unroll
      for (int e = 0; e < 8; ++e) { As[lr][lc + e] = ga[e]; Bs[lr][lc + e] = gb[e]; }
    }
    __syncthreads();
#pragma unroll
    for (int k2 = 0; k2 < 32; ++k2) {
      float al[4], bl[4];
#pragma unroll
      for (int i = 0; i < 4; ++i) { al[i] = As[tr + 16 * i][k2]; bl[i] = Bs[tc + 16 * i][k2]; }
#pragma unroll
      for (int i = 0; i < 4; ++i)
#pragma unroll
        for (int j = 0; j < 4; ++j) acc[i][j] += al[i] * bl[j];
    }
  }
#pragma unroll
  for (int i = 0; i < 4; ++i) {
    const int m = bm + tr + 16 * i;                 // chunk-local row
#pragma unroll
    for (int j = 0; j < 4; ++j) {
      const int nn = bn + tc + 16 * j;
      const float v = acc[i][j] + bi[nn];
      if (nn < DI) XIN[(size_t)(m + 3) * DI + nn] = f2b(v);
      else         ZS [(size_t)m * DI + (nn - DI)] = f2b(silu_f(v));
    }
  }
}

// --------------------------------------------------------------------------
// kscan: chunk fused conv+dt+scan+gate. Grid (DI/16), 256 thr = 16d x 16n.
// XIN rows: 0..2 = history, 3..Tc+2 = chunk. h carried in ws across chunks.
// Writes G (separate buffer).
// --------------------------------------------------------------------------
__global__ __launch_bounds__(256)
void kscan(const bf16* __restrict__ XIN, const bf16* __restrict__ ZS,
           bf16* __restrict__ G,
           const float* __restrict__ cw, const float* __restrict__ cb,
           const float* __restrict__ Wdt, const float* __restrict__ bdt,
           const float* __restrict__ A_log, const float* __restrict__ Bm,
           const float* __restrict__ Cm,
           float* __restrict__ hstate, int zeroH)
{
  __shared__ float Wl[16][33];
  __shared__ float x32[64][33];
  __shared__ float xc[67][17];
  __shared__ float dts[64 * 16];
  __shared__ float us [64 * 16];
  __shared__ float ys [64 * 16];

  const int tid = threadIdx.x;
  const int n  = tid & 15;
  const int dl = tid >> 4;
  const int d0 = blockIdx.x * 16;
  const int d  = d0 + dl;

  const float Af = -__expf(A_log[(size_t)d * DS + n]);
  const float Bf = Bm[(size_t)d * DS + n];
  const float Cf = Cm[(size_t)d * DS + n];
  const float w0 = cw[d * DC + 0], w1 = cw[d * DC + 1];
  const float w2 = cw[d * DC + 2], w3 = cw[d * DC + 3];
  const float c0 = cb[d];
  const float bdtv = bdt[d];

  for (int e = tid; e < 16 * DTR; e += 256)
    Wl[e >> 5][e & 31] = Wdt[(size_t)(d0 + (e >> 5)) * DTR + (e & 31)];

  float h = zeroH ? 0.0f : hstate[(size_t)d * DS + n];

  for (int t0 = 0; t0 < Tc; t0 += 64) {
    __syncthreads();
    for (int e = tid; e < 64 * 32; e += 256) {
      const int tl = e >> 5, r = e & 31;
      x32[tl][r] = b2f(XIN[(size_t)(3 + t0 + tl) * DI + r]);
    }
    for (int e = tid; e < 67 * 16; e += 256) {
      const int i = e >> 4, dd = e & 15;
      xc[i][dd] = b2f(XIN[(size_t)(t0 + i) * DI + d0 + dd]);  // rows t0..t0+66
    }
    __syncthreads();

#pragma unroll
    for (int q = 0; q < 4; ++q) {
      const int tl = n + 16 * q;
      const float cv = c0 + w0 * xc[tl][dl] + w1 * xc[tl + 1][dl]
                          + w2 * xc[tl + 2][dl] + w3 * xc[tl + 3][dl];
      us[tl * 16 + dl] = silu_f(cv);
      float a = bdtv;
#pragma unroll
      for (int r = 0; r < DTR; ++r) a += x32[tl][r] * Wl[dl][r];
      dts[tl * 16 + dl] = softplus_f(a);
    }
    __syncthreads();

    for (int tl = 0; tl < 64; ++tl) {
      const float dtv = dts[tl * 16 + dl];
      const float uv  = us [tl * 16 + dl];
      h = h * __expf(dtv * Af) + (dtv * Bf) * uv;
      float y = h * Cf;
      y += __shfl_xor(y, 1);
      y += __shfl_xor(y, 2);
      y += __shfl_xor(y, 4);
      y += __shfl_xor(y, 8);
      if (n == 0) ys[tl * 16 + dl] = y;
    }
    __syncthreads();

    for (int e = tid; e < 64 * 16; e += 256) {
      const int tl = e >> 4, dd = e & 15;
      const size_t gi = (size_t)(t0 + tl) * DI + d0 + dd;
      G[gi] = f2b(ys[e] * b2f(ZS[gi]));
    }
  }

  hstate[(size_t)d * DS + n] = h;
}

// --------------------------------------------------------------------------
// k2: chunk GEMM  out += G @ Wo^T  (fp32 accumulate into fp32 out;
// bias/residual already there via kpre).  Grid (DM/64, Tc/64).
// --------------------------------------------------------------------------
__global__ __launch_bounds__(256)
void k2(const bf16* __restrict__ G, const float* __restrict__ Wo,
        float* __restrict__ out)
{
  __shared__ float As[64][36];
  __shared__ float Bs[64][36];
  const int tid = threadIdx.x;
  const int bm = blockIdx.y * 64;
  const int bn = blockIdx.x * 64;
  const int tr = tid >> 4, tc = tid & 15;
  const int lr = tid >> 2, lc = (tid & 3) * 8;
  const int K = DI;

  float acc[4][4] = {};
  for (int k0 = 0; k0 < K; k0 += 32) {
    __syncthreads();
    {
      const bf16*  ga = G  + (size_t)(bm + lr) * K + k0 + lc;
      const float* gb = Wo + (size_t)(bn + lr) * K + k0 + lc;
#pragma unroll
      for (int e = 0; e < 8; ++e) { As[lr][lc + e] = b2f(ga[e]); Bs[lr][lc + e] = gb[e]; }
    }
    __syncthreads();
#pragma unroll
    for (int k2i = 0; k2i < 32; ++k2i) {
      float al[4], bl[4];
#pragma unroll
      for (int i = 0; i < 4; ++i) { al[i] = As[tr + 16 * i][k2i]; bl[i] = Bs[tc + 16 * i][k2i]; }
#pragma unroll
      for (int i = 0; i < 4; ++i)
#pragma unroll
        for (int j = 0; j < 4; ++j) acc[i][j] += al[i] * bl[j];
    }
  }
#pragma unroll
  for (int i = 0; i < 4; ++i) {
    const int m = bm + tr + 16 * i;
#pragma unroll
    for (int j = 0; j < 4; ++j) {
      const int nn = bn + tc + 16 * j;
      const size_t oi = (size_t)m * DM + nn;
      out[oi] += acc[i][j];
    }
  }
}

// --------------------------------------------------------------------------
extern "C" void kernel_launch(void* const* d_in, const int* in_sizes, int n_in,
                              void* d_out, int out_size, void* d_ws, size_t ws_size,
                              hipStream_t stream)
{
  const float* x    = (const float*)d_in[0];
  const float* Wi   = (const float*)d_in[1];
  const float* bi   = (const float*)d_in[2];
  const float* cw   = (const float*)d_in[3];
  const float* cb   = (const float*)d_in[4];
  const float* Wdt  = (const float*)d_in[5];
  const float* bdt  = (const float*)d_in[6];
  const float* Alog = (const float*)d_in[7];
  const float* Bm   = (const float*)d_in[8];
  const float* Cm   = (const float*)d_in[9];
  const float* Dv   = (const float*)d_in[10];
  const float* Wo   = (const float*)d_in[11];
  const float* bo   = (const float*)d_in[12];
  float* out = (float*)d_out;   // fp32 output per reference dtype

  char* ws = (char*)d_ws;
  float* MEANP = (float*)(ws);
  float* HST   = (float*)(ws + 256);
  bf16*  XIN   = (bf16*)(ws + 131328);
  bf16*  ZS    = (bf16*)(ws + 1192192);
  bf16*  G     = (bf16*)(ws + 2240768);   // total 3,289,344 B

  kmean<<<1, 256, 0, stream>>>(Dv, MEANP);
  kpre<<<dim3(DM / 256, Mrows), 256, 0, stream>>>(x, bo, MEANP, out);

  for (int b = 0; b < Bdim; ++b) {
    for (int c = 0; c < Tdim / Tc; ++c) {
      const size_t rowbase = (size_t)b * Tdim + (size_t)c * Tc;
      if (c == 0) kzero<<<24, 256, 0, stream>>>(XIN);
      else        ktail<<<24, 256, 0, stream>>>(XIN);
      k1<<<dim3(2 * DI / 64, Tc / 64), 256, 0, stream>>>(
          x + rowbase * DM, Wi, bi, XIN, ZS);
      kscan<<<dim3(DI / 16), 256, 0, stream>>>(
          XIN, ZS, G, cw, cb, Wdt, bdt, Alog, Bm, Cm, HST, c == 0 ? 1 : 0);
      k2<<<dim3(DM / 64, Tc / 64), 256, 0, stream>>>(
          G, Wo, out + rowbase * DM);
    }
  }
}